// Round 10
// baseline (595.324 us; speedup 1.0000x reference)
//
#include <hip/hip_runtime.h>
#include <stdint.h>

typedef __attribute__((ext_vector_type(4))) float f32x4;
typedef __attribute__((ext_vector_type(8))) short short8;
typedef __attribute__((ext_vector_type(8))) _Float16 half8;
typedef unsigned short u16;
typedef unsigned int u32;
typedef unsigned char u8;

#define DEV static __device__ __forceinline__

DEV u32 fbits(float f) { union { float f; u32 u; } v; v.f = f; return v.u; }
DEV float bits2f(u32 u) { union { u32 u; float f; } v; v.u = u; return v.f; }

// bf16 round-to-nearest-even (for the split-fp32 proj GEMM)
DEV u16 f2bf_rne(float f) {
  u32 u = fbits(f);
  u32 r = u + 0x7fffu + ((u >> 16) & 1u);
  return (u16)(r >> 16);
}
DEV u16 f2bf_trunc(float f) { return (u16)(fbits(f) >> 16); }
DEV float bf2f(u16 h) { return bits2f(((u32)h) << 16); }
DEV void split2(float f, u16& h, u16& l) {
  h = f2bf_rne(f);
  float r = f - bf2f(h);
  l = f2bf_trunc(r);
}

// fp16 helpers
DEV u16 f2h(float f) { union { _Float16 h; u16 u; } v; v.h = (_Float16)f; return v.u; }
DEV float h2f(u16 u) { union { u16 u; _Float16 h; } v; v.u = u; return (float)v.h; }
DEV half8 as_h8(short8 s) { union { short8 s; half8 h; } u; u.s = s; return u.h; }
DEV uint2 pk4h(f32x4 v) {
  uint2 w;
  w.x = (u32)f2h(v[0]) | ((u32)f2h(v[1]) << 16);
  w.y = (u32)f2h(v[2]) | ((u32)f2h(v[3]) << 16);
  return w;
}

// fast branch-light OCP e4m3fn encoder (RNE; sat 448; subnormals handled)
DEV u8 f32_to_e4m3(float f) {
  u32 u = fbits(f);
  u32 s = (u >> 24) & 0x80u;
  u32 a = u & 0x7fffffffu;
  if (a >= 0x43e00000u) return (u8)(s | 0x7e);   // >=448 (or NaN) -> max
  if (a < 0x3a800000u) return (u8)s;             // < 2^-10 -> +-0
  int e = (int)(a >> 23);
  u32 man = (a & 0x7fffffu) | 0x800000u;
  int E = e - 127 + 7;
  int sh = (E >= 1) ? 20 : (21 - E);             // extra shift for subnormals
  u32 q = (man + ((1u << (sh - 1)) - 1u + ((man >> sh) & 1u))) >> sh;
  if (E < 1) E = 1;
  if (q >= 16) { q >>= 1; ++E; }
  if (E >= 16) return (u8)(s | 0x7e);
  u32 enc = (q >= 8) ? (((u32)E << 3) | (q - 8)) : q;
  return (u8)(s | enc);
}

DEV void gll16(const void* gsrc, char* ldsp) {
  __builtin_amdgcn_global_load_lds(
      (const __attribute__((address_space(1))) u32*)gsrc,
      (__attribute__((address_space(3))) u32*)ldsp,
      16, 0, 0);
}

DEV f32x4 mfma16(short8 a, short8 b, f32x4 c) {
  return __builtin_amdgcn_mfma_f32_16x16x32_bf16(a, b, c, 0, 0, 0);
}
DEV f32x4 mfmah(half8 a, half8 b, f32x4 c) {
  return __builtin_amdgcn_mfma_f32_16x16x32_f16(a, b, c, 0, 0, 0);
}
DEV f32x4 mfma8(long a, long b, f32x4 c) {
  return __builtin_amdgcn_mfma_f32_16x16x32_fp8_fp8(a, b, c, 0, 0, 0);
}

// ---------------------------------------------------------------------------
// K1: C = A[M][512]*B[N][512]^T fp32-emulated (split bf16, 3 MFMA). Epilogues:
// MODE 0 (q): o0=fp16(5C); o1=fp16 residual; o2=e4m3(fp16 value)  row-major
// MODE 2 (k): o0=fp16(C) FRAG-MAJOR u16; o2=e4m3(4096*residual) FRAG-MAJOR u8.
//   Both share frag geometry: elem((b*32+kt)*64 + dck*4 + t4, lane=lg*16+lmr, j)
//   i.e. idx = (frag*64 + lane)*8 + j   (1 frag = A-operand of one 16x16x32)
// ---------------------------------------------------------------------------
template<int MODE>
__global__ __launch_bounds__(256, 1) void proj_qk(
    const float* __restrict__ A, const float* __restrict__ Bm,
    u16* __restrict__ o0, u16* __restrict__ o1, u8* __restrict__ o2,
    float scale)
{
  extern __shared__ char smem[];
  const int tid = threadIdx.x;
  const int lane = tid & 63, wv = tid >> 6;
  const int wm = wv & 1, wn = wv >> 1;
  const int lm = lane & 15, lg = lane >> 4;
  const int n0 = blockIdx.x * 128, m0 = blockIdx.y * 128;

  f32x4 acc[4][4] = {};

  for (int k0 = 0; k0 < 512; k0 += 64) {
    __syncthreads();
    #pragma unroll
    for (int i = 0; i < 8; ++i) {
      int c = i * 256 + tid;
      int row = c >> 4, c4 = c & 15;
      f32x4 av = *(const f32x4*)(A + (size_t)(m0 + row) * 512 + (k0 + c4 * 4));
      f32x4 bv = *(const f32x4*)(Bm + (size_t)(n0 + row) * 512 + (k0 + c4 * 4));
      int base = row * 128 + ((((c4 >> 1) ^ (row & 7)) << 4) + (c4 & 1) * 8);
      u16 ah[4], al[4], bh[4], bl[4];
      #pragma unroll
      for (int j = 0; j < 4; ++j) { split2(av[j], ah[j], al[j]); split2(bv[j], bh[j], bl[j]); }
      *(ushort4*)(smem +         base) = make_ushort4(ah[0], ah[1], ah[2], ah[3]);
      *(ushort4*)(smem + 16384 + base) = make_ushort4(al[0], al[1], al[2], al[3]);
      *(ushort4*)(smem + 32768 + base) = make_ushort4(bh[0], bh[1], bh[2], bh[3]);
      *(ushort4*)(smem + 49152 + base) = make_ushort4(bl[0], bl[1], bl[2], bl[3]);
    }
    __syncthreads();
    #pragma unroll
    for (int ks = 0; ks < 2; ++ks) {
      short8 fah[4], fal[4], fbh[4], fbl[4];
      #pragma unroll
      for (int t = 0; t < 4; ++t) {
        int ar = wm * 64 + t * 16 + lm;
        int ac = (((ks * 4 + lg) ^ (ar & 7)) << 4);
        fah[t] = *(const short8*)(smem +         ar * 128 + ac);
        fal[t] = *(const short8*)(smem + 16384 + ar * 128 + ac);
        int br = wn * 64 + t * 16 + lm;
        int bc = (((ks * 4 + lg) ^ (br & 7)) << 4);
        fbh[t] = *(const short8*)(smem + 32768 + br * 128 + bc);
        fbl[t] = *(const short8*)(smem + 49152 + br * 128 + bc);
      }
      #pragma unroll
      for (int mt = 0; mt < 4; ++mt)
        #pragma unroll
        for (int nt = 0; nt < 4; ++nt) {
          acc[mt][nt] = mfma16(fah[mt], fbh[nt], acc[mt][nt]);
          acc[mt][nt] = mfma16(fah[mt], fbl[nt], acc[mt][nt]);
          acc[mt][nt] = mfma16(fal[mt], fbh[nt], acc[mt][nt]);
        }
    }
  }
  #pragma unroll
  for (int mt = 0; mt < 4; ++mt)
    #pragma unroll
    for (int nt = 0; nt < 4; ++nt)
      #pragma unroll
      for (int i = 0; i < 4; ++i) {
        float v = acc[mt][nt][i] * scale;
        int m = m0 + wm * 64 + mt * 16 + lg * 4 + i;
        int n = n0 + wn * 64 + nt * 16 + lm;
        u16 h = f2h(v);
        float res = v - h2f(h);
        if (MODE == 0) {
          size_t idx = (size_t)m * 512 + n;
          o0[idx] = h;
          o1[idx] = f2h(res);
          o2[idx] = f32_to_e4m3(h2f(h));
        } else {
          int b2 = m >> 11, sL = m & 2047;
          int kt = sL >> 6, t4s = (sL >> 4) & 3, lma = sL & 15;
          int dck = n >> 5, lga = (n >> 3) & 3, j = n & 7;
          size_t idx = (((size_t)((b2 * 32 + kt) * 64 + dck * 4 + t4s)) * 64
                        + (lga * 16 + lma)) * 8 + j;
          o0[idx] = h;
          o2[idx] = f32_to_e4m3(res * 4096.f);
        }
      }
}

// ---------------------------------------------------------------------------
// K1v: v^T = Wv * x^T, single-pass fp16, FRAG-MAJOR output for PV A-frags:
//   vf idx = ((((b*32+kt)*32 + d16)*2 + ks)*64 + lg*16+lmr)*8 + j
// ---------------------------------------------------------------------------
__global__ __launch_bounds__(256, 1) void proj_v(
    const float* __restrict__ A, const float* __restrict__ Bm,
    u16* __restrict__ o0)
{
  extern __shared__ char smem[];
  const int tid = threadIdx.x;
  const int lane = tid & 63, wv = tid >> 6;
  const int wm = wv & 1, wn = wv >> 1;
  const int lm = lane & 15, lg = lane >> 4;
  const int n0 = blockIdx.x * 128, m0 = blockIdx.y * 128;

  f32x4 acc[4][4] = {};

  for (int k0 = 0; k0 < 512; k0 += 64) {
    __syncthreads();
    #pragma unroll
    for (int i = 0; i < 8; ++i) {
      int c = i * 256 + tid;
      int row = c >> 4, c4 = c & 15;
      f32x4 av = *(const f32x4*)(A + (size_t)(m0 + row) * 512 + (k0 + c4 * 4));
      f32x4 bv = *(const f32x4*)(Bm + (size_t)(n0 + row) * 512 + (k0 + c4 * 4));
      int base = row * 128 + ((c4 ^ (2 * (row & 7))) << 3);
      *(uint2*)(smem +         base) = pk4h(av);
      *(uint2*)(smem + 16384 + base) = pk4h(bv);
    }
    __syncthreads();
    #pragma unroll
    for (int ks = 0; ks < 2; ++ks) {
      half8 fa[4], fb[4];
      #pragma unroll
      for (int t = 0; t < 4; ++t) {
        int ar = wm * 64 + t * 16 + lm;
        fa[t] = as_h8(*(const short8*)(smem + ar * 128 + (((ks * 4 + lg) ^ (ar & 7)) << 4)));
        int br = wn * 64 + t * 16 + lm;
        fb[t] = as_h8(*(const short8*)(smem + 16384 + br * 128 + (((ks * 4 + lg) ^ (br & 7)) << 4)));
      }
      #pragma unroll
      for (int mt = 0; mt < 4; ++mt)
        #pragma unroll
        for (int nt = 0; nt < 4; ++nt)
          acc[mt][nt] = mfmah(fa[mt], fb[nt], acc[mt][nt]);
    }
  }
  #pragma unroll
  for (int mt = 0; mt < 4; ++mt)
    #pragma unroll
    for (int nt = 0; nt < 4; ++nt)
      #pragma unroll
      for (int i = 0; i < 4; ++i) {
        int m = m0 + wm * 64 + mt * 16 + lg * 4 + i;   // d
        int n = n0 + wn * 64 + nt * 16 + lm;           // global token
        int b2 = n >> 11, sT = n & 2047;
        int kt = sT >> 6, kloc = sT & 63;
        int ks = kloc >> 5, lga = (kloc >> 3) & 3, j = kloc & 7;
        int d16 = m >> 4, lmr = m & 15;
        size_t idx = ((((size_t)((b2 * 32 + kt) * 32 + d16)) * 2 + ks) * 64
                      + (lga * 16 + lmr)) * 8 + j;
        o0[idx] = f2h(acc[mt][nt][i]);
      }
}

// ---------------------------------------------------------------------------
// K2: fused flash attention, ZERO K/V LDS-staging. 8 waves (2/SIMD), QBLK=64.
// K/V/kl8 stored frag-major in ws -> A-frags are coalesced 1KB L2 loads.
// d-split QK: wave-group g2 computes d-half g2*256..+256 (partial S), high
// group writes partials to LDS, low group combines + softmax (lane-local,
// swapped QK). d-split PV: wave wv owns d-rows wv*64..+64, P via LDS.
// Only 2 barriers/kt. Q-hi+q8 in regs (half-d); Q-lo in LDS.
// LDS: QL 64K | SX 16K | P 8K | alpha 256B = 88.3KB
// ---------------------------------------------------------------------------
#define QLB 0
#define SXB 65536
#define PBF 81920
#define ABF 90112
#define ALDS 90368

__global__ __launch_bounds__(512, 2) void attn_fused(
    const u16* __restrict__ qh_g, const u16* __restrict__ ql_g,
    const u8* __restrict__ q8_g, const u16* __restrict__ kh2,
    const u8* __restrict__ kl8, const u16* __restrict__ vf,
    float* __restrict__ out)
{
  extern __shared__ char smem[];
  const int tid = threadIdx.x;
  const int lane = tid & 63, wv = tid >> 6;
  const int w4 = wv & 3, g2 = wv >> 2;
  const int lm = lane & 15, lg = lane >> 4;
  const int b = blockIdx.x, qt = blockIdx.y;   // batch fastest -> XCD-local K/V
  const int srow = w4 * 16 + lm;               // lane's q-col
  const size_t qrow0 = (size_t)(b * 2048 + qt * 64);

  // ---- stage Q-lo [64][512] fp16 -> LDS (16B granules swizzled ^row&7)
  #pragma unroll
  for (int it = 0; it < 8; ++it) {
    int slot = it * 512 + tid;
    int row = slot >> 6, ch = slot & 63, sc = ch ^ (row & 7);
    gll16(ql_g + (qrow0 + row) * 512 + sc * 8, smem + QLB + slot * 16);
  }
  // ---- Q-hi + q8 for this wave's d-half -> registers (loaded ONCE)
  half8 qhr[8]; long q8r[8];
  {
    const u16* qph = qh_g + (qrow0 + srow) * 512 + g2 * 256;
    const u8*  qp8 = q8_g + (qrow0 + srow) * 512 + g2 * 256;
    #pragma unroll
    for (int j = 0; j < 8; ++j) {
      qhr[j] = as_h8(*(const short8*)(qph + j * 32 + lg * 8));
      q8r[j] = *(const long*)(qp8 + j * 32 + lg * 8);
    }
  }
  asm volatile("s_waitcnt vmcnt(0)" ::: "memory");
  __syncthreads();

  float m = -3e38f, l = 0.f;
  f32x4 oacc[4][4] = {};

  for (int kt = 0; kt < 32; ++kt) {
    // ======== QK: this wave's 256-d half, frags straight from L2 ========
    f32x4 sacc[4] = {}, s3[4] = {};
    const size_t fb = ((size_t)((b * 32 + kt) * 16 + g2 * 8)) * 4 * 512;
    #pragma unroll
    for (int lc = 0; lc < 8; ++lc) {
      const size_t gb = fb + (size_t)lc * 2048;
      half8 bqh = qhr[lc];
      long  b8  = q8r[lc];
      int gq = (g2 * 32 + lc * 4 + lg) ^ (srow & 7);
      half8 bql = as_h8(*(const short8*)(smem + QLB + srow * 1024 + gq * 16));
      #pragma unroll
      for (int t4 = 0; t4 < 4; ++t4) {
        half8 akh = as_h8(*(const short8*)(kh2 + gb + t4 * 512 + lane * 8));
        long  akl = *(const long*)(kl8 + gb + t4 * 512 + lane * 8);
        sacc[t4] = mfmah(akh, bqh, sacc[t4]);
        sacc[t4] = mfmah(akh, bql, sacc[t4]);
        s3[t4]   = mfma8(akl, b8, s3[t4]);
      }
    }
    #pragma unroll
    for (int t4 = 0; t4 < 4; ++t4)
      sacc[t4] += s3[t4] * 0.000244140625f;   // fp8 pass scaled 2^-12

    // ======== partial-S exchange: high d-half -> low ========
    if (g2) {
      #pragma unroll
      for (int t4 = 0; t4 < 4; ++t4)
        *(f32x4*)(smem + SXB + w4 * 4096 + t4 * 1024 + lane * 16) = sacc[t4];
    }
    asm volatile("s_waitcnt lgkmcnt(0)" ::: "memory");
    __builtin_amdgcn_s_barrier();
    __builtin_amdgcn_sched_barrier(0);
    // ---- prefetch V frags (independent of P; hides under softmax)
    half8 av[4][2];
    const size_t vb = ((size_t)((b * 32 + kt) * 32 + wv * 4)) * 2 * 512;
    #pragma unroll
    for (int dt = 0; dt < 4; ++dt)
      #pragma unroll
      for (int ks = 0; ks < 2; ++ks)
        av[dt][ks] = as_h8(*(const short8*)(vf + vb + (dt * 2 + ks) * 512 + lane * 8));
    if (!g2) {
      #pragma unroll
      for (int t4 = 0; t4 < 4; ++t4)
        sacc[t4] += *(const f32x4*)(smem + SXB + w4 * 4096 + t4 * 1024 + lane * 16);
      // ---- online softmax (lane-local in q), P + alpha to LDS
      float mx = fmaxf(fmaxf(fmaxf(sacc[0][0], sacc[0][1]), fmaxf(sacc[0][2], sacc[0][3])),
                       fmaxf(fmaxf(sacc[1][0], sacc[1][1]), fmaxf(sacc[1][2], sacc[1][3])));
      mx = fmaxf(mx, fmaxf(fmaxf(fmaxf(sacc[2][0], sacc[2][1]), fmaxf(sacc[2][2], sacc[2][3])),
                           fmaxf(fmaxf(sacc[3][0], sacc[3][1]), fmaxf(sacc[3][2], sacc[3][3]))));
      mx = fmaxf(mx, __shfl_xor(mx, 16, 64));
      mx = fmaxf(mx, __shfl_xor(mx, 32, 64));
      float alpha;
      if (__any(mx > m)) {            // exact rescale-skip
        float mn = fmaxf(m, mx);
        alpha = __expf(m - mn);
        m = mn;
        l *= alpha;
      } else {
        alpha = 1.0f;
      }
      float sm = 0.f;
      #pragma unroll
      for (int t4 = 0; t4 < 4; ++t4)
        #pragma unroll
        for (int i = 0; i < 4; ++i) {
          float pv = __expf(sacc[t4][i] - m);
          sacc[t4][i] = pv;
          sm += pv;
        }
      sm += __shfl_xor(sm, 16, 64);
      sm += __shfl_xor(sm, 32, 64);
      l += sm;
      // P[q=srow][k], 8B granules swizzled g ^= (q&7)<<1
      #pragma unroll
      for (int t4 = 0; t4 < 4; ++t4)
        *(uint2*)(smem + PBF + srow * 128 + (((t4 * 4 + lg) ^ ((lm & 7) << 1)) << 3))
            = pk4h(sacc[t4]);
      if (lg == 0) *(float*)(smem + ABF + srow * 4) = alpha;
    }
    asm volatile("s_waitcnt lgkmcnt(0)" ::: "memory");
    __builtin_amdgcn_s_barrier();
    __builtin_amdgcn_sched_barrier(0);
    // ======== PV: wave owns d-rows wv*64..+64, all 64 q-cols ========
    float a4[4]; half8 pp[4][2];
    #pragma unroll
    for (int st = 0; st < 4; ++st) {
      a4[st] = *(const float*)(smem + ABF + (st * 16 + lm) * 4);
      #pragma unroll
      for (int ks = 0; ks < 2; ++ks) {
        int g0 = ks * 8 + lg * 2;
        uint2 u0 = *(const uint2*)(smem + PBF + (st * 16 + lm) * 128 +
                                   ((g0 ^ ((lm & 7) << 1)) << 3));
        uint2 u1 = *(const uint2*)(smem + PBF + (st * 16 + lm) * 128 +
                                   (((g0 + 1) ^ ((lm & 7) << 1)) << 3));
        union { uint4 u; short8 s; } pw;
        pw.u = make_uint4(u0.x, u0.y, u1.x, u1.y);
        pp[st][ks] = as_h8(pw.s);
      }
    }
    #pragma unroll
    for (int dt = 0; dt < 4; ++dt)
      #pragma unroll
      for (int st = 0; st < 4; ++st)
        oacc[dt][st] *= a4[st];
    #pragma unroll
    for (int dt = 0; dt < 4; ++dt)
      #pragma unroll
      for (int ks = 0; ks < 2; ++ks)
        #pragma unroll
        for (int st = 0; st < 4; ++st)
          oacc[dt][st] = mfmah(av[dt][ks], pp[st][ks], oacc[dt][st]);
  }
  // ---- finalize: l broadcast (all waves need it), divide, coalesced store
  __syncthreads();
  if (!g2 && lg == 0) *(float*)(smem + ABF + srow * 4) = l;
  __syncthreads();
  float li[4];
  #pragma unroll
  for (int st = 0; st < 4; ++st)
    li[st] = 1.0f / *(const float*)(smem + ABF + (st * 16 + lm) * 4);
  float* ob = out + ((size_t)b << 20) + qt * 64;
  #pragma unroll
  for (int dt = 0; dt < 4; ++dt)
    #pragma unroll
    for (int st = 0; st < 4; ++st)
      #pragma unroll
      for (int i = 0; i < 4; ++i) {
        int d = wv * 64 + dt * 16 + lg * 4 + i;
        ob[(size_t)d * 2048 + st * 16 + lm] = oacc[dt][st][i] * li[st];
      }
}

// ---------------------------------------------------------------------------
extern "C" void kernel_launch(void* const* d_in, const int* in_sizes, int n_in,
                              void* d_out, int out_size, void* d_ws, size_t ws_size,
                              hipStream_t stream) {
  (void)in_sizes; (void)n_in; (void)out_size; (void)ws_size;
  const float* x  = (const float*)d_in[0];
  const float* Wk = (const float*)d_in[1];
  const float* Wq = (const float*)d_in[2];
  const float* Wv = (const float*)d_in[3];
  float* out = (float*)d_out;

  const size_t SZ = (size_t)16384 * 512;
  u16* qh  = (u16*)d_ws;           // fp16 [16384][512] row-major
  u16* ql  = qh + SZ;              // fp16 row-major
  u16* kh2 = ql + SZ;              // fp16 FRAG-MAJOR
  u16* vf  = kh2 + SZ;             // fp16 FRAG-MAJOR
  u8*  q8  = (u8*)(vf + SZ);       // e4m3 row-major
  u8*  kl8 = q8 + SZ;              // e4m3 (4096*kl) FRAG-MAJOR

  (void)hipFuncSetAttribute(reinterpret_cast<const void*>(&proj_qk<0>),
                            hipFuncAttributeMaxDynamicSharedMemorySize, 65536);
  (void)hipFuncSetAttribute(reinterpret_cast<const void*>(&proj_qk<2>),
                            hipFuncAttributeMaxDynamicSharedMemorySize, 65536);
  (void)hipFuncSetAttribute(reinterpret_cast<const void*>(&proj_v),
                            hipFuncAttributeMaxDynamicSharedMemorySize, 32768);
  (void)hipFuncSetAttribute(reinterpret_cast<const void*>(&attn_fused),
                            hipFuncAttributeMaxDynamicSharedMemorySize, ALDS);

  dim3 pblk(256), ablk(512);
  // q = 5 * x @ Wq^T (scale folded so scores come out pre-scaled)
  proj_qk<0><<<dim3(4, 128), pblk, 65536, stream>>>(x, Wq, qh, ql, q8, 5.0f);
  proj_qk<2><<<dim3(4, 128), pblk, 65536, stream>>>(x, Wk, kh2, nullptr, kl8, 1.0f);
  proj_v    <<<dim3(128, 4), pblk, 32768, stream>>>(Wv, x, vf);
  attn_fused<<<dim3(8, 32), ablk, ALDS, stream>>>(qh, ql, q8, kh2, kl8, vf, out);
}